// Round 2
// baseline (117.530 us; speedup 1.0000x reference)
//
#include <hip/hip_runtime.h>
#include <hip/hip_bf16.h>

// Problem constants
// B=32768, P=8; aff/mat vocab 16 -> 256 (aff,mat) pairs
// part table: 256 pairs x 256 outputs (bf16)
// obj GEMM: pooled[B,256] @ W_obj[:,192:448]^T

typedef float  f32x4  __attribute__((ext_vector_type(4)));
typedef short  s16x8  __attribute__((ext_vector_type(8)));

__device__ __forceinline__ unsigned short f2bf_rne(float x) {
    unsigned u = __float_as_uint(x);
    u += 0x7FFFu + ((u >> 16) & 1u);
    return (unsigned short)(u >> 16);
}
__device__ __forceinline__ float bf2f(unsigned short s) {
    return __uint_as_float(((unsigned)s) << 16);
}

// ws layout (bytes)
#define WS_PART_TABLE 0          // 256*256 short = 131072
#define WS_WP2T       131072     // 256*256 short = 131072  (W_obj[:,192:448] transposed-to-[n][k], bf16)
#define WS_TT         262144     // 16*256 f32 (b_obj folded in)
#define WS_TO         278528     // 64*256 f32
#define WS_TS         344064     // 32*256 f32
// total = 376832 bytes

__global__ __launch_bounds__(256) void precompute_kernel(
    const float* __restrict__ aff_emb, const float* __restrict__ mat_emb,
    const float* __restrict__ task_emb, const float* __restrict__ obj_emb,
    const float* __restrict__ state_emb,
    const float* __restrict__ W_part, const float* __restrict__ b_part,
    const float* __restrict__ W_obj, const float* __restrict__ b_obj,
    char* __restrict__ ws)
{
    short* part_table = (short*)(ws + WS_PART_TABLE);
    short* wp2t       = (short*)(ws + WS_WP2T);
    float* Tt         = (float*)(ws + WS_TT);
    float* To         = (float*)(ws + WS_TO);
    float* Ts         = (float*)(ws + WS_TS);

    int bid = blockIdx.x, tid = threadIdx.x;
    __shared__ float rowv[128];

    if (bid < 256) {
        // part table: pair = a*16+m
        int a = bid >> 4, m = bid & 15;
        if (tid < 64)       rowv[tid] = aff_emb[a*64 + tid];
        else if (tid < 128) rowv[tid] = mat_emb[m*64 + (tid-64)];
        __syncthreads();
        float s = b_part[tid];
        const float* w = &W_part[tid*128];
        #pragma unroll
        for (int k = 0; k < 128; k += 4) {
            float4 wv = *(const float4*)&w[k];
            s += rowv[k]*wv.x + rowv[k+1]*wv.y + rowv[k+2]*wv.z + rowv[k+3]*wv.w;
        }
        part_table[bid*256 + tid] = (short)f2bf_rne(fmaxf(s, 0.f));
    } else if (bid < 368) {
        // categorical tables
        int rr = bid - 256;
        const float* emb; int koff; float* dst;
        if (rr < 16)      { emb = &task_emb[rr*64];        koff = 0;   dst = &Tt[rr*256]; }
        else if (rr < 80) { emb = &obj_emb[(rr-16)*64];    koff = 64;  dst = &To[(rr-16)*256]; }
        else              { emb = &state_emb[(rr-80)*64];  koff = 128; dst = &Ts[(rr-80)*256]; }
        if (tid < 64) rowv[tid] = emb[tid];
        __syncthreads();
        float s = (rr < 16) ? b_obj[tid] : 0.f;
        const float* w = &W_obj[tid*448 + koff];
        #pragma unroll
        for (int k = 0; k < 64; k += 4) {
            float4 wv = *(const float4*)&w[k];
            s += rowv[k]*wv.x + rowv[k+1]*wv.y + rowv[k+2]*wv.z + rowv[k+3]*wv.w;
        }
        dst[tid] = s;
    } else {
        // W_obj[:,192:448] -> wp2t[n][k] bf16
        int n = bid - 368;
        wp2t[n*256 + tid] = (short)f2bf_rne(W_obj[n*448 + 192 + tid]);
    }
}

__global__ __launch_bounds__(256, 2) void main_kernel(
    const int* __restrict__ aff_idx, const int* __restrict__ mat_idx,
    const int* __restrict__ task_idx, const int* __restrict__ obj_idx,
    const int* __restrict__ state_idx,
    const char* __restrict__ ws, float* __restrict__ out)
{
    const short* part_table = (const short*)(ws + WS_PART_TABLE);
    const short* wp2t       = (const short*)(ws + WS_WP2T);
    const float* Tt         = (const float*)(ws + WS_TT);
    const float* To         = (const float*)(ws + WS_TO);
    const float* Ts         = (const float*)(ws + WS_TS);

    __shared__ short pooled[16*264];   // 16 rows x 256 elems, padded stride 264 (2-way conflict = free)
    __shared__ int   pair_s[16*8];
    __shared__ int   tos_s[48];        // [3][16] task/obj/state per row

    int tid  = threadIdx.x;
    int wave = tid >> 6, lane = tid & 63;
    int l15 = lane & 15, l4 = lane >> 4;

    // B fragments (persist across tiles): wave covers output cols [wave*64, wave*64+64)
    // B-frag layout: col = lane&15, k = (lane>>4)*8 + j  (8 consecutive k -> 16B load)
    s16x8 bfrag[4][8];
    #pragma unroll
    for (int nt = 0; nt < 4; ++nt) {
        int n = wave*64 + nt*16 + l15;
        #pragma unroll
        for (int ks = 0; ks < 8; ++ks) {
            int k = ks*32 + l4*8;
            bfrag[nt][ks] = *(const s16x8*)&wp2t[n*256 + k];
        }
    }

    for (int it = 0; it < 4; ++it) {
        int tile = blockIdx.x * 4 + it;
        int row0 = tile * 16;
        __syncthreads();   // protect LDS from previous tile's readers
        if (tid < 128) {
            int r = tid >> 3, j = tid & 7;
            int a = aff_idx[(row0+r)*8 + j];
            int m = mat_idx[(row0+r)*8 + j];
            pair_s[r*8 + j] = (a*16 + m) * 256;   // element offset into part_table
        } else if (tid < 176) {
            int u = tid - 128;
            int r = u & 15, wh = u >> 4;
            int row = row0 + r;
            int v = (wh == 0) ? task_idx[row] : (wh == 1) ? obj_idx[row] : state_idx[row];
            tos_s[wh*16 + r] = v;
        }
        __syncthreads();

        // ---- pooling: thread (r = tid>>4, e = tid&15) covers elems [e*16, e*16+16) of row r
        {
            int r = tid >> 4, e = tid & 15;
            float mx[16];
            #pragma unroll
            for (int q = 0; q < 16; ++q) mx[q] = 0.f;  // relu'd entries >= 0, so 0-init is exact
            #pragma unroll
            for (int p = 0; p < 8; ++p) {
                int off = pair_s[r*8 + p] + e*16;
                s16x8 v0 = *(const s16x8*)&part_table[off];
                s16x8 v1 = *(const s16x8*)&part_table[off + 8];
                #pragma unroll
                for (int q = 0; q < 8; ++q) {
                    mx[q]     = fmaxf(mx[q],     bf2f((unsigned short)v0[q]));
                    mx[q + 8] = fmaxf(mx[q + 8], bf2f((unsigned short)v1[q]));
                }
            }
            s16x8 o0, o1;
            #pragma unroll
            for (int q = 0; q < 8; ++q) {
                o0[q] = (short)(__float_as_uint(mx[q])     >> 16);  // exact: mx is an exact bf16 value
                o1[q] = (short)(__float_as_uint(mx[q + 8]) >> 16);
            }
            *(s16x8*)&pooled[r*264 + e*16]     = o0;
            *(s16x8*)&pooled[r*264 + e*16 + 8] = o1;
        }
        __syncthreads();

        // ---- MFMA: D[16 rows][16 cols] per n-tile; A row = lane&15, k = (lane>>4)*8+j
        f32x4 acc[4];
        #pragma unroll
        for (int nt = 0; nt < 4; ++nt) acc[nt] = (f32x4){0.f, 0.f, 0.f, 0.f};
        #pragma unroll
        for (int ks = 0; ks < 8; ++ks) {
            s16x8 af = *(const s16x8*)&pooled[l15*264 + ks*32 + l4*8];
            #pragma unroll
            for (int nt = 0; nt < 4; ++nt)
                acc[nt] = __builtin_amdgcn_mfma_f32_16x16x32_bf16(af, bfrag[nt][ks], acc[nt], 0, 0, 0);
        }

        // ---- epilogue: C/D layout col = lane&15, row = (lane>>4)*4 + reg
        #pragma unroll
        for (int nt = 0; nt < 4; ++nt) {
            int col = wave*64 + nt*16 + l15;
            #pragma unroll
            for (int reg = 0; reg < 4; ++reg) {
                int rl  = l4*4 + reg;
                int row = row0 + rl;
                int t = tos_s[rl], o = tos_s[16 + rl], s = tos_s[32 + rl];
                float v = acc[nt][reg] + Tt[t*256 + col] + To[o*256 + col] + Ts[s*256 + col];
                out[row*256 + col] = fmaxf(v, 0.f);
            }
        }
    }
}

extern "C" void kernel_launch(void* const* d_in, const int* in_sizes, int n_in,
                              void* d_out, int out_size, void* d_ws, size_t ws_size,
                              hipStream_t stream) {
    const int*   aff_idx   = (const int*)d_in[0];
    const int*   mat_idx   = (const int*)d_in[1];
    const int*   task_idx  = (const int*)d_in[2];
    const int*   obj_idx   = (const int*)d_in[3];
    const int*   state_idx = (const int*)d_in[4];
    const float* aff_emb   = (const float*)d_in[5];
    const float* mat_emb   = (const float*)d_in[6];
    const float* task_emb  = (const float*)d_in[7];
    const float* obj_emb   = (const float*)d_in[8];
    const float* state_emb = (const float*)d_in[9];
    const float* W_part    = (const float*)d_in[10];
    const float* b_part    = (const float*)d_in[11];
    const float* W_obj     = (const float*)d_in[12];
    const float* b_obj     = (const float*)d_in[13];

    precompute_kernel<<<624, 256, 0, stream>>>(
        aff_emb, mat_emb, task_emb, obj_emb, state_emb,
        W_part, b_part, W_obj, b_obj, (char*)d_ws);

    main_kernel<<<512, 256, 0, stream>>>(
        aff_idx, mat_idx, task_idx, obj_idx, state_idx,
        (const char*)d_ws, (float*)d_out);
}